// Round 1
// baseline (1414.673 us; speedup 1.0000x reference)
//
#include <hip/hip_runtime.h>

// Attention (B=4, T=2048, dim=2048, H=16, hd=128) on gfx950.
// Pipeline: cast->bf16 | QKV gemms (MFMA, A*B^T) | RoPE | flash attention | out gemm.
// Workspace layout (needs 192 MiB):
//   xb[2^24] wqb wkb wvb wob[2^22 each] qb[2^24] kb[2^24] vtb[2^24] aout[2^24]  (all bf16)

using floatx4  = __attribute__((ext_vector_type(4))) float;
using short8   = __attribute__((ext_vector_type(8))) short;
using ushortx4 = __attribute__((ext_vector_type(4))) unsigned short;

#define DEVFN static __device__ __forceinline__

DEVFN unsigned short f2bf(float f) {          // RNE float->bf16
  unsigned u = __builtin_bit_cast(unsigned, f);
  u += 0x7fffu + ((u >> 16) & 1u);
  return (unsigned short)(u >> 16);
}
DEVFN float bf2f(unsigned short h) {
  return __builtin_bit_cast(float, ((unsigned)h) << 16);
}

DEVFN void async_cp16(const unsigned short* g, unsigned short* l) {
  __builtin_amdgcn_global_load_lds(
      (const __attribute__((address_space(1))) void*)g,
      (__attribute__((address_space(3))) void*)l,
      16, 0, 0);
}

// ---------------- cast fp32 -> bf16 (vectorized) ----------------
__global__ __launch_bounds__(256) void cast_kernel(const float4* __restrict__ in,
                                                   ushortx4* __restrict__ out) {
  long u = (long)blockIdx.x * 256 + threadIdx.x;
  float4 v = in[u];
  out[u] = (ushortx4){f2bf(v.x), f2bf(v.y), f2bf(v.z), f2bf(v.w)};
}

// ---------------- RoPE in-place on Q,K [64][2048][128] bf16 ----------------
__global__ __launch_bounds__(256) void rope_kernel(unsigned short* __restrict__ Q,
                                                   unsigned short* __restrict__ K,
                                                   const float* __restrict__ pos) {
  long idx = (long)blockIdx.x * 256 + threadIdx.x;   // 2^24 threads
  unsigned short* arr = (idx >> 23) ? K : Q;
  long rem = idx & ((1L << 23) - 1);
  long row = rem >> 6;          // bh*2048 + t
  int j = (int)(rem & 63);      // pair index 0..63
  int t = (int)(row & 2047);
  // freq_j = 10000^(-j/64) = exp2(-j * log2(10000)/64)
  float ang = pos[t] * exp2f(-0.20762051f * (float)j);
  float s = sinf(ang), c = cosf(ang);
  unsigned short* base = arr + (row << 7);
  float x1 = bf2f(base[j]), x2 = bf2f(base[j + 64]);
  base[j]      = f2bf(x1 * c - x2 * s);
  base[j + 64] = f2bf(x2 * c + x1 * s);
}

// ---------------- GEMM: C[m,n] = sum_k A[m,k]*B[n,k] + bias[n] ----------------
// M=8192 N=2048 K=2048. 128x128 tile, BK=64, 4 waves (2x2 of 64x64), mfma 16x16x32.
// LDS XOR-swizzle: phys_chunk = chunk ^ (row&7)  (8 chunks of 16B per 64-elem row).
// MODE 0: bf16 out [B,H,T,hd]   (Q,K pre-RoPE)
// MODE 1: bf16 out [B,H,hd,T]   (V transposed)
// MODE 2: fp32 out [M,N]        (final projection)
template <int MODE>
__global__ __launch_bounds__(256) void gemm_bt(const unsigned short* __restrict__ A,
                                               const unsigned short* __restrict__ Bw,
                                               const float* __restrict__ bias,
                                               void* __restrict__ Cout) {
  constexpr int K = 2048;
  __shared__ __align__(16) unsigned short lds_a[128 * 64];
  __shared__ __align__(16) unsigned short lds_b[128 * 64];
  const int tid = threadIdx.x;
  const int wave = tid >> 6, lane = tid & 63;
  const int ln15 = lane & 15, quad = lane >> 4;
  const int wr = wave >> 1, wc = wave & 1;
  const int m0 = blockIdx.y * 128;
  const int n0 = blockIdx.x * 128;

  floatx4 acc[4][4];
#pragma unroll
  for (int i = 0; i < 4; ++i)
#pragma unroll
    for (int j = 0; j < 4; ++j) acc[i][j] = (floatx4){0.f, 0.f, 0.f, 0.f};

  for (int k0 = 0; k0 < K; k0 += 64) {
    __syncthreads();
#pragma unroll
    for (int j = 0; j < 4; ++j) {   // A tile: 1024 16B units
      int u = j * 256 + tid;
      int row = u >> 3;
      int c = (u & 7) ^ (row & 7);
      async_cp16(A + (long)(m0 + row) * K + (k0 + c * 8),
                 lds_a + (j * 256 + wave * 64) * 8);
    }
#pragma unroll
    for (int j = 0; j < 4; ++j) {   // B tile
      int u = j * 256 + tid;
      int row = u >> 3;
      int c = (u & 7) ^ (row & 7);
      async_cp16(Bw + (long)(n0 + row) * K + (k0 + c * 8),
                 lds_b + (j * 256 + wave * 64) * 8);
    }
    asm volatile("s_waitcnt vmcnt(0)" ::: "memory");
    __syncthreads();
#pragma unroll
    for (int ks = 0; ks < 2; ++ks) {
      short8 af[4], bf[4];
#pragma unroll
      for (int mi = 0; mi < 4; ++mi) {
        int row = wr * 64 + mi * 16 + ln15;
        int phys = (ks * 4 + quad) ^ (row & 7);
        af[mi] = *(const short8*)(lds_a + row * 64 + phys * 8);
      }
#pragma unroll
      for (int ni = 0; ni < 4; ++ni) {
        int row = wc * 64 + ni * 16 + ln15;
        int phys = (ks * 4 + quad) ^ (row & 7);
        bf[ni] = *(const short8*)(lds_b + row * 64 + phys * 8);
      }
#pragma unroll
      for (int mi = 0; mi < 4; ++mi)
#pragma unroll
        for (int ni = 0; ni < 4; ++ni)
          acc[mi][ni] = __builtin_amdgcn_mfma_f32_16x16x32_bf16(af[mi], bf[ni],
                                                                acc[mi][ni], 0, 0, 0);
    }
  }

  // epilogue. C layout: row = quad*4+reg, col = ln15 (per 16x16 tile)
#pragma unroll
  for (int mi = 0; mi < 4; ++mi) {
#pragma unroll
    for (int ni = 0; ni < 4; ++ni) {
      int n = n0 + wc * 64 + ni * 16 + ln15;
      float bv = bias[n];
      int mbase = m0 + wr * 64 + mi * 16 + quad * 4;
      if (MODE == 0) {
        int h = n >> 7, d = n & 127;
#pragma unroll
        for (int r = 0; r < 4; ++r) {
          int m = mbase + r;
          int b = m >> 11, t = m & 2047;
          ((unsigned short*)Cout)[((((long)(b * 16 + h)) << 11) + t) * 128 + d] =
              f2bf(acc[mi][ni][r] + bv);
        }
      } else if (MODE == 1) {
        int h = n >> 7, d = n & 127;
        int b = mbase >> 11, t = mbase & 2047;   // 4 consecutive t, same b
        ushortx4 v;
#pragma unroll
        for (int r = 0; r < 4; ++r) v[r] = f2bf(acc[mi][ni][r] + bv);
        *(ushortx4*)((unsigned short*)Cout +
                     ((((long)(b * 16 + h)) << 7) + d) * 2048 + t) = v;
      } else {
#pragma unroll
        for (int r = 0; r < 4; ++r) {
          int m = mbase + r;
          ((float*)Cout)[(long)m * 2048 + n] = acc[mi][ni][r] + bv;
        }
      }
    }
  }
}

// ---------------- flash attention ----------------
// grid (16 q-tiles, 64 bh). 4 waves x 32 q-rows. K-tile & Vt-tile in LDS (64KB).
// Q frags in registers; P round-trips through kbuf (reused) in bf16.
__global__ __launch_bounds__(256, 2) void flash_kernel(
    const unsigned short* __restrict__ Q,    // [64][2048][128]
    const unsigned short* __restrict__ Kmat, // [64][2048][128]
    const unsigned short* __restrict__ Vt,   // [64][128][2048]
    unsigned short* __restrict__ Out) {      // [4][2048][2048]
  constexpr int T = 2048;
  constexpr float SCALE = 0.08838834764831845f;  // 1/sqrt(128)
  __shared__ __align__(16) unsigned short kbuf[128 * 128];
  __shared__ __align__(16) unsigned short vbuf[128 * 128];

  const int tid = threadIdx.x;
  const int wave = tid >> 6, lane = tid & 63;
  const int ln15 = lane & 15, quad = lane >> 4;
  const int q0 = blockIdx.x * 128;
  const int bh = blockIdx.y;

  const unsigned short* Qb = Q + (long)bh * T * 128;
  const unsigned short* Kb = Kmat + (long)bh * T * 128;
  const unsigned short* Vb = Vt + (long)bh * 128 * T;

  // stage Q tile -> registers (swizzle: 16 chunks/row, phys = c ^ (row&15))
#pragma unroll
  for (int j = 0; j < 8; ++j) {
    int u = j * 256 + tid;
    int row = u >> 4;
    int c = (u & 15) ^ (row & 15);
    async_cp16(Qb + (long)(q0 + row) * 128 + c * 8, kbuf + (j * 256 + wave * 64) * 8);
  }
  asm volatile("s_waitcnt vmcnt(0)" ::: "memory");
  __syncthreads();
  short8 qf[2][4];
#pragma unroll
  for (int mi = 0; mi < 2; ++mi)
#pragma unroll
    for (int ks = 0; ks < 4; ++ks) {
      int row = wave * 32 + mi * 16 + ln15;
      int phys = (ks * 4 + quad) ^ (row & 15);
      qf[mi][ks] = *(const short8*)(kbuf + row * 128 + phys * 8);
    }
  __syncthreads();

  floatx4 oacc[2][8];
#pragma unroll
  for (int mi = 0; mi < 2; ++mi)
#pragma unroll
    for (int nj = 0; nj < 8; ++nj) oacc[mi][nj] = (floatx4){0.f, 0.f, 0.f, 0.f};
  float mst[2][4], lst[2][4];
#pragma unroll
  for (int mi = 0; mi < 2; ++mi)
#pragma unroll
    for (int r = 0; r < 4; ++r) { mst[mi][r] = -1e30f; lst[mi][r] = 0.f; }

  for (int kb = 0; kb < 16; ++kb) {
    __syncthreads();   // previous iter's P/V readers done
#pragma unroll
    for (int j = 0; j < 8; ++j) {   // K tile [key 128][d 128]
      int u = j * 256 + tid;
      int row = u >> 4;
      int c = (u & 15) ^ (row & 15);
      async_cp16(Kb + (long)(kb * 128 + row) * 128 + c * 8,
                 kbuf + (j * 256 + wave * 64) * 8);
    }
#pragma unroll
    for (int j = 0; j < 8; ++j) {   // Vt tile [d 128][key 128]
      int u = j * 256 + tid;
      int row = u >> 4;
      int c = (u & 15) ^ (row & 15);
      async_cp16(Vb + (long)row * T + kb * 128 + c * 8,
                 vbuf + (j * 256 + wave * 64) * 8);
    }
    asm volatile("s_waitcnt vmcnt(0)" ::: "memory");
    __syncthreads();

    // S = Q K^T (raw, scale folded into softmax)
    floatx4 sacc[2][8];
#pragma unroll
    for (int mi = 0; mi < 2; ++mi)
#pragma unroll
      for (int ni = 0; ni < 8; ++ni) sacc[mi][ni] = (floatx4){0.f, 0.f, 0.f, 0.f};
#pragma unroll
    for (int ks = 0; ks < 4; ++ks) {
      short8 bfr[8];
#pragma unroll
      for (int ni = 0; ni < 8; ++ni) {
        int row = ni * 16 + ln15;
        int phys = (ks * 4 + quad) ^ ln15;
        bfr[ni] = *(const short8*)(kbuf + row * 128 + phys * 8);
      }
#pragma unroll
      for (int mi = 0; mi < 2; ++mi)
#pragma unroll
        for (int ni = 0; ni < 8; ++ni)
          sacc[mi][ni] = __builtin_amdgcn_mfma_f32_16x16x32_bf16(qf[mi][ks], bfr[ni],
                                                                 sacc[mi][ni], 0, 0, 0);
    }

    // online softmax per q-row (row r of quad, 16 lanes hold 16 cols x 8 tiles)
#pragma unroll
    for (int mi = 0; mi < 2; ++mi)
#pragma unroll
      for (int r = 0; r < 4; ++r) {
        float mx = -1e30f;
#pragma unroll
        for (int ni = 0; ni < 8; ++ni) mx = fmaxf(mx, sacc[mi][ni][r]);
#pragma unroll
        for (int off = 1; off < 16; off <<= 1) mx = fmaxf(mx, __shfl_xor(mx, off, 16));
        mx *= SCALE;
        float mold = mst[mi][r];
        float mnew = fmaxf(mold, mx);
        float alpha = __expf(mold - mnew);
        float rs = 0.f;
#pragma unroll
        for (int ni = 0; ni < 8; ++ni) {
          float p = __expf(sacc[mi][ni][r] * SCALE - mnew);
          sacc[mi][ni][r] = p;
          rs += p;
        }
#pragma unroll
        for (int off = 1; off < 16; off <<= 1) rs += __shfl_xor(rs, off, 16);
        mst[mi][r] = mnew;
        lst[mi][r] = lst[mi][r] * alpha + rs;
#pragma unroll
        for (int nj = 0; nj < 8; ++nj) oacc[mi][nj][r] *= alpha;
      }

    __syncthreads();   // all waves done reading kbuf as K
    // write P (bf16) into kbuf; each wave writes only its own 32 rows
#pragma unroll
    for (int mi = 0; mi < 2; ++mi)
#pragma unroll
      for (int ni = 0; ni < 8; ++ni) {
        int col = ni * 16 + ln15;
        int cc = col >> 3, w8 = col & 7;
#pragma unroll
        for (int r = 0; r < 4; ++r) {
          int m = wave * 32 + mi * 16 + quad * 4 + r;
          kbuf[m * 128 + (cc ^ (m & 15)) * 8 + w8] = f2bf(sacc[mi][ni][r]);
        }
      }

    // O += P * V (reads own P rows + vbuf; same-wave LDS ordering is in-order)
#pragma unroll
    for (int ks = 0; ks < 4; ++ks) {
      short8 af[2], bv[8];
#pragma unroll
      for (int mi = 0; mi < 2; ++mi) {
        int m = wave * 32 + mi * 16 + ln15;
        int phys = (ks * 4 + quad) ^ (m & 15);
        af[mi] = *(const short8*)(kbuf + m * 128 + phys * 8);
      }
#pragma unroll
      for (int nj = 0; nj < 8; ++nj) {
        int row = nj * 16 + ln15;
        int phys = (ks * 4 + quad) ^ ln15;
        bv[nj] = *(const short8*)(vbuf + row * 128 + phys * 8);
      }
#pragma unroll
      for (int mi = 0; mi < 2; ++mi)
#pragma unroll
        for (int nj = 0; nj < 8; ++nj)
          oacc[mi][nj] = __builtin_amdgcn_mfma_f32_16x16x32_bf16(af[mi], bv[nj],
                                                                 oacc[mi][nj], 0, 0, 0);
    }
  }

  // epilogue: O /= l, write bf16 [b][t][h*128+d]
  const int b = bh >> 4, h = bh & 15;
#pragma unroll
  for (int mi = 0; mi < 2; ++mi)
#pragma unroll
    for (int r = 0; r < 4; ++r) {
      float rinv = 1.f / lst[mi][r];
      int t = q0 + wave * 32 + mi * 16 + quad * 4 + r;
      unsigned short* orow = Out + (((long)(b * T + t)) << 11) + h * 128;
#pragma unroll
      for (int nj = 0; nj < 8; ++nj)
        orow[nj * 16 + ln15] = f2bf(oacc[mi][nj][r] * rinv);
    }
}

extern "C" void kernel_launch(void* const* d_in, const int* in_sizes, int n_in,
                              void* d_out, int out_size, void* d_ws, size_t ws_size,
                              hipStream_t stream) {
  const float* x    = (const float*)d_in[0];
  const float* pos  = (const float*)d_in[1];
  const float* wq_w = (const float*)d_in[2];
  const float* wq_b = (const float*)d_in[3];
  const float* wk_w = (const float*)d_in[4];
  const float* wk_b = (const float*)d_in[5];
  const float* wv_w = (const float*)d_in[6];
  const float* wv_b = (const float*)d_in[7];
  const float* wo_w = (const float*)d_in[8];
  const float* wo_b = (const float*)d_in[9];

  unsigned short* xb  = (unsigned short*)d_ws;
  unsigned short* wqb = xb  + (1u << 24);
  unsigned short* wkb = wqb + (1u << 22);
  unsigned short* wvb = wkb + (1u << 22);
  unsigned short* wob = wvb + (1u << 22);
  unsigned short* qb  = wob + (1u << 22);
  unsigned short* kb  = qb  + (1u << 24);
  unsigned short* vtb = kb  + (1u << 24);
  unsigned short* ab  = vtb + (1u << 24);   // attention output, bf16 [8192][2048]

  cast_kernel<<<16384, 256, 0, stream>>>((const float4*)x, (ushortx4*)xb);
  cast_kernel<<<4096, 256, 0, stream>>>((const float4*)wq_w, (ushortx4*)wqb);
  cast_kernel<<<4096, 256, 0, stream>>>((const float4*)wk_w, (ushortx4*)wkb);
  cast_kernel<<<4096, 256, 0, stream>>>((const float4*)wv_w, (ushortx4*)wvb);
  cast_kernel<<<4096, 256, 0, stream>>>((const float4*)wo_w, (ushortx4*)wob);

  dim3 ggrid(16, 64);
  gemm_bt<0><<<ggrid, 256, 0, stream>>>(xb, wqb, wq_b, (void*)qb);
  gemm_bt<0><<<ggrid, 256, 0, stream>>>(xb, wkb, wk_b, (void*)kb);
  gemm_bt<1><<<ggrid, 256, 0, stream>>>(xb, wvb, wv_b, (void*)vtb);
  rope_kernel<<<65536, 256, 0, stream>>>(qb, kb, pos);
  flash_kernel<<<dim3(16, 64), 256, 0, stream>>>(qb, kb, vtb, ab);
  gemm_bt<2><<<ggrid, 256, 0, stream>>>(ab, wob, wo_b, d_out);
}

// Round 2
// 1397.750 us; speedup vs baseline: 1.0121x; 1.0121x over previous
//
#include <hip/hip_runtime.h>

// Attention (B=4, T=2048, dim=2048, H=16, hd=128) on gfx950.
// Pipeline: cast->bf16 | QKV gemms (MFMA, A*B^T) | RoPE | flash attention | out gemm.
// R2: XCD-aware 1D grid swizzles. Flash: all 16 q-tiles of one bh -> same XCD
//     (K/V fetched from HBM once per bh, re-reads hit per-XCD L2).
//     GEMM: 8 m-tiles per XCD resident -> A tiles L2-resident.
// Workspace layout (needs 192 MiB):
//   xb[2^24] wqb wkb wvb wob[2^22 each] qb[2^24] kb[2^24] vtb[2^24] aout[2^24]  (all bf16)

using floatx4  = __attribute__((ext_vector_type(4))) float;
using short8   = __attribute__((ext_vector_type(8))) short;
using ushortx4 = __attribute__((ext_vector_type(4))) unsigned short;

#define DEVFN static __device__ __forceinline__

DEVFN unsigned short f2bf(float f) {          // RNE float->bf16
  unsigned u = __builtin_bit_cast(unsigned, f);
  u += 0x7fffu + ((u >> 16) & 1u);
  return (unsigned short)(u >> 16);
}
DEVFN float bf2f(unsigned short h) {
  return __builtin_bit_cast(float, ((unsigned)h) << 16);
}

DEVFN void async_cp16(const unsigned short* g, unsigned short* l) {
  __builtin_amdgcn_global_load_lds(
      (const __attribute__((address_space(1))) void*)g,
      (__attribute__((address_space(3))) void*)l,
      16, 0, 0);
}

// ---------------- cast fp32 -> bf16 (vectorized) ----------------
__global__ __launch_bounds__(256) void cast_kernel(const float4* __restrict__ in,
                                                   ushortx4* __restrict__ out) {
  long u = (long)blockIdx.x * 256 + threadIdx.x;
  float4 v = in[u];
  out[u] = (ushortx4){f2bf(v.x), f2bf(v.y), f2bf(v.z), f2bf(v.w)};
}

// ---------------- RoPE in-place on Q,K [64][2048][128] bf16 ----------------
__global__ __launch_bounds__(256) void rope_kernel(unsigned short* __restrict__ Q,
                                                   unsigned short* __restrict__ K,
                                                   const float* __restrict__ pos) {
  long idx = (long)blockIdx.x * 256 + threadIdx.x;   // 2^24 threads
  unsigned short* arr = (idx >> 23) ? K : Q;
  long rem = idx & ((1L << 23) - 1);
  long row = rem >> 6;          // bh*2048 + t
  int j = (int)(rem & 63);      // pair index 0..63
  int t = (int)(row & 2047);
  // freq_j = 10000^(-j/64) = exp2(-j * log2(10000)/64)
  float ang = pos[t] * exp2f(-0.20762051f * (float)j);
  float s = sinf(ang), c = cosf(ang);
  unsigned short* base = arr + (row << 7);
  float x1 = bf2f(base[j]), x2 = bf2f(base[j + 64]);
  base[j]      = f2bf(x1 * c - x2 * s);
  base[j + 64] = f2bf(x2 * c + x1 * s);
}

// ---------------- GEMM: C[m,n] = sum_k A[m,k]*B[n,k] + bias[n] ----------------
// M=8192 N=2048 K=2048. 128x128 tile, BK=64, 4 waves (2x2 of 64x64), mfma 16x16x32.
// 1D grid 1024, XCD swizzle: xcd = bid&7 owns m-tiles xcd*8..xcd*8+7 (A L2-resident).
// LDS XOR-swizzle: phys_chunk = chunk ^ (row&7)  (8 chunks of 16B per 64-elem row).
// MODE 0: bf16 out [B,H,T,hd]   (Q,K pre-RoPE)
// MODE 1: bf16 out [B,H,hd,T]   (V transposed)
// MODE 2: fp32 out [M,N]        (final projection)
template <int MODE>
__global__ __launch_bounds__(256) void gemm_bt(const unsigned short* __restrict__ A,
                                               const unsigned short* __restrict__ Bw,
                                               const float* __restrict__ bias,
                                               void* __restrict__ Cout) {
  constexpr int K = 2048;
  __shared__ __align__(16) unsigned short lds_a[128 * 64];
  __shared__ __align__(16) unsigned short lds_b[128 * 64];
  const int tid = threadIdx.x;
  const int wave = tid >> 6, lane = tid & 63;
  const int ln15 = lane & 15, quad = lane >> 4;
  const int wr = wave >> 1, wc = wave & 1;
  const int bid = blockIdx.x;
  const int xcd = bid & 7, sl = bid >> 3;          // sl in [0,128)
  const int m0 = (xcd * 8 + (sl & 7)) * 128;       // 8 m-tiles per XCD
  const int n0 = (sl >> 3) * 128;                  // 16 n-tiles

  floatx4 acc[4][4];
#pragma unroll
  for (int i = 0; i < 4; ++i)
#pragma unroll
    for (int j = 0; j < 4; ++j) acc[i][j] = (floatx4){0.f, 0.f, 0.f, 0.f};

  for (int k0 = 0; k0 < K; k0 += 64) {
    __syncthreads();
#pragma unroll
    for (int j = 0; j < 4; ++j) {   // A tile: 1024 16B units
      int u = j * 256 + tid;
      int row = u >> 3;
      int c = (u & 7) ^ (row & 7);
      async_cp16(A + (long)(m0 + row) * K + (k0 + c * 8),
                 lds_a + (j * 256 + wave * 64) * 8);
    }
#pragma unroll
    for (int j = 0; j < 4; ++j) {   // B tile
      int u = j * 256 + tid;
      int row = u >> 3;
      int c = (u & 7) ^ (row & 7);
      async_cp16(Bw + (long)(n0 + row) * K + (k0 + c * 8),
                 lds_b + (j * 256 + wave * 64) * 8);
    }
    asm volatile("s_waitcnt vmcnt(0)" ::: "memory");
    __syncthreads();
#pragma unroll
    for (int ks = 0; ks < 2; ++ks) {
      short8 af[4], bf[4];
#pragma unroll
      for (int mi = 0; mi < 4; ++mi) {
        int row = wr * 64 + mi * 16 + ln15;
        int phys = (ks * 4 + quad) ^ (row & 7);
        af[mi] = *(const short8*)(lds_a + row * 64 + phys * 8);
      }
#pragma unroll
      for (int ni = 0; ni < 4; ++ni) {
        int row = wc * 64 + ni * 16 + ln15;
        int phys = (ks * 4 + quad) ^ (row & 7);
        bf[ni] = *(const short8*)(lds_b + row * 64 + phys * 8);
      }
#pragma unroll
      for (int mi = 0; mi < 4; ++mi)
#pragma unroll
        for (int ni = 0; ni < 4; ++ni)
          acc[mi][ni] = __builtin_amdgcn_mfma_f32_16x16x32_bf16(af[mi], bf[ni],
                                                                acc[mi][ni], 0, 0, 0);
    }
  }

  // epilogue. C layout: row = quad*4+reg, col = ln15 (per 16x16 tile)
#pragma unroll
  for (int mi = 0; mi < 4; ++mi) {
#pragma unroll
    for (int ni = 0; ni < 4; ++ni) {
      int n = n0 + wc * 64 + ni * 16 + ln15;
      float bv = bias[n];
      int mbase = m0 + wr * 64 + mi * 16 + quad * 4;
      if (MODE == 0) {
        int h = n >> 7, d = n & 127;
#pragma unroll
        for (int r = 0; r < 4; ++r) {
          int m = mbase + r;
          int b = m >> 11, t = m & 2047;
          ((unsigned short*)Cout)[((((long)(b * 16 + h)) << 11) + t) * 128 + d] =
              f2bf(acc[mi][ni][r] + bv);
        }
      } else if (MODE == 1) {
        int h = n >> 7, d = n & 127;
        int b = mbase >> 11, t = mbase & 2047;   // 4 consecutive t, same b
        ushortx4 v;
#pragma unroll
        for (int r = 0; r < 4; ++r) v[r] = f2bf(acc[mi][ni][r] + bv);
        *(ushortx4*)((unsigned short*)Cout +
                     ((((long)(b * 16 + h)) << 7) + d) * 2048 + t) = v;
      } else {
#pragma unroll
        for (int r = 0; r < 4; ++r) {
          int m = mbase + r;
          ((float*)Cout)[(long)m * 2048 + n] = acc[mi][ni][r] + bv;
        }
      }
    }
  }
}

// ---------------- flash attention ----------------
// 1D grid 1024, XCD swizzle: xcd = bid&7; bh = xcd*8 + (s>>4); qt = s&15.
// All 16 q-tiles of one bh -> same XCD, consecutive dispatch => K/V re-reads hit L2.
// 4 waves x 32 q-rows. K-tile & Vt-tile in LDS (64KB -> 2 blocks/CU).
// Q frags in registers; P round-trips through kbuf (reused) in bf16.
__global__ __launch_bounds__(256, 2) void flash_kernel(
    const unsigned short* __restrict__ Q,    // [64][2048][128]
    const unsigned short* __restrict__ Kmat, // [64][2048][128]
    const unsigned short* __restrict__ Vt,   // [64][128][2048]
    unsigned short* __restrict__ Out) {      // [4][2048][2048]
  constexpr int T = 2048;
  constexpr float SCALE = 0.08838834764831845f;  // 1/sqrt(128)
  __shared__ __align__(16) unsigned short kbuf[128 * 128];
  __shared__ __align__(16) unsigned short vbuf[128 * 128];

  const int tid = threadIdx.x;
  const int wave = tid >> 6, lane = tid & 63;
  const int ln15 = lane & 15, quad = lane >> 4;
  const int bid = blockIdx.x;
  const int xcd = bid & 7, sl = bid >> 3;     // sl in [0,128)
  const int bh = xcd * 8 + (sl >> 4);         // 8 bh per XCD
  const int q0 = (sl & 15) * 128;             // 16 q-tiles, consecutive on the XCD

  const unsigned short* Qb = Q + (long)bh * T * 128;
  const unsigned short* Kb = Kmat + (long)bh * T * 128;
  const unsigned short* Vb = Vt + (long)bh * 128 * T;

  // stage Q tile -> registers (swizzle: 16 chunks/row, phys = c ^ (row&15))
#pragma unroll
  for (int j = 0; j < 8; ++j) {
    int u = j * 256 + tid;
    int row = u >> 4;
    int c = (u & 15) ^ (row & 15);
    async_cp16(Qb + (long)(q0 + row) * 128 + c * 8, kbuf + (j * 256 + wave * 64) * 8);
  }
  asm volatile("s_waitcnt vmcnt(0)" ::: "memory");
  __syncthreads();
  short8 qf[2][4];
#pragma unroll
  for (int mi = 0; mi < 2; ++mi)
#pragma unroll
    for (int ks = 0; ks < 4; ++ks) {
      int row = wave * 32 + mi * 16 + ln15;
      int phys = (ks * 4 + quad) ^ (row & 15);
      qf[mi][ks] = *(const short8*)(kbuf + row * 128 + phys * 8);
    }
  __syncthreads();

  floatx4 oacc[2][8];
#pragma unroll
  for (int mi = 0; mi < 2; ++mi)
#pragma unroll
    for (int nj = 0; nj < 8; ++nj) oacc[mi][nj] = (floatx4){0.f, 0.f, 0.f, 0.f};
  float mst[2][4], lst[2][4];
#pragma unroll
  for (int mi = 0; mi < 2; ++mi)
#pragma unroll
    for (int r = 0; r < 4; ++r) { mst[mi][r] = -1e30f; lst[mi][r] = 0.f; }

  for (int kb = 0; kb < 16; ++kb) {
    __syncthreads();   // previous iter's P/V readers done
#pragma unroll
    for (int j = 0; j < 8; ++j) {   // K tile [key 128][d 128]
      int u = j * 256 + tid;
      int row = u >> 4;
      int c = (u & 15) ^ (row & 15);
      async_cp16(Kb + (long)(kb * 128 + row) * 128 + c * 8,
                 kbuf + (j * 256 + wave * 64) * 8);
    }
#pragma unroll
    for (int j = 0; j < 8; ++j) {   // Vt tile [d 128][key 128]
      int u = j * 256 + tid;
      int row = u >> 4;
      int c = (u & 15) ^ (row & 15);
      async_cp16(Vb + (long)row * T + kb * 128 + c * 8,
                 vbuf + (j * 256 + wave * 64) * 8);
    }
    asm volatile("s_waitcnt vmcnt(0)" ::: "memory");
    __syncthreads();

    // S = Q K^T (raw, scale folded into softmax)
    floatx4 sacc[2][8];
#pragma unroll
    for (int mi = 0; mi < 2; ++mi)
#pragma unroll
      for (int ni = 0; ni < 8; ++ni) sacc[mi][ni] = (floatx4){0.f, 0.f, 0.f, 0.f};
#pragma unroll
    for (int ks = 0; ks < 4; ++ks) {
      short8 bfr[8];
#pragma unroll
      for (int ni = 0; ni < 8; ++ni) {
        int row = ni * 16 + ln15;
        int phys = (ks * 4 + quad) ^ ln15;
        bfr[ni] = *(const short8*)(kbuf + row * 128 + phys * 8);
      }
#pragma unroll
      for (int mi = 0; mi < 2; ++mi)
#pragma unroll
        for (int ni = 0; ni < 8; ++ni)
          sacc[mi][ni] = __builtin_amdgcn_mfma_f32_16x16x32_bf16(qf[mi][ks], bfr[ni],
                                                                 sacc[mi][ni], 0, 0, 0);
    }

    // online softmax per q-row (row r of quad, 16 lanes hold 16 cols x 8 tiles)
#pragma unroll
    for (int mi = 0; mi < 2; ++mi)
#pragma unroll
      for (int r = 0; r < 4; ++r) {
        float mx = -1e30f;
#pragma unroll
        for (int ni = 0; ni < 8; ++ni) mx = fmaxf(mx, sacc[mi][ni][r]);
#pragma unroll
        for (int off = 1; off < 16; off <<= 1) mx = fmaxf(mx, __shfl_xor(mx, off, 16));
        mx *= SCALE;
        float mold = mst[mi][r];
        float mnew = fmaxf(mold, mx);
        float alpha = __expf(mold - mnew);
        float rs = 0.f;
#pragma unroll
        for (int ni = 0; ni < 8; ++ni) {
          float p = __expf(sacc[mi][ni][r] * SCALE - mnew);
          sacc[mi][ni][r] = p;
          rs += p;
        }
#pragma unroll
        for (int off = 1; off < 16; off <<= 1) rs += __shfl_xor(rs, off, 16);
        mst[mi][r] = mnew;
        lst[mi][r] = lst[mi][r] * alpha + rs;
#pragma unroll
        for (int nj = 0; nj < 8; ++nj) oacc[mi][nj][r] *= alpha;
      }

    __syncthreads();   // all waves done reading kbuf as K
    // write P (bf16) into kbuf; each wave writes only its own 32 rows
#pragma unroll
    for (int mi = 0; mi < 2; ++mi)
#pragma unroll
      for (int ni = 0; ni < 8; ++ni) {
        int col = ni * 16 + ln15;
        int cc = col >> 3, w8 = col & 7;
#pragma unroll
        for (int r = 0; r < 4; ++r) {
          int m = wave * 32 + mi * 16 + quad * 4 + r;
          kbuf[m * 128 + (cc ^ (m & 15)) * 8 + w8] = f2bf(sacc[mi][ni][r]);
        }
      }

    // O += P * V (reads own P rows + vbuf; same-wave LDS ordering is in-order)
#pragma unroll
    for (int ks = 0; ks < 4; ++ks) {
      short8 af[2], bv[8];
#pragma unroll
      for (int mi = 0; mi < 2; ++mi) {
        int m = wave * 32 + mi * 16 + ln15;
        int phys = (ks * 4 + quad) ^ (m & 15);
        af[mi] = *(const short8*)(kbuf + m * 128 + phys * 8);
      }
#pragma unroll
      for (int nj = 0; nj < 8; ++nj) {
        int row = nj * 16 + ln15;
        int phys = (ks * 4 + quad) ^ ln15;
        bv[nj] = *(const short8*)(vbuf + row * 128 + phys * 8);
      }
#pragma unroll
      for (int mi = 0; mi < 2; ++mi)
#pragma unroll
        for (int nj = 0; nj < 8; ++nj)
          oacc[mi][nj] = __builtin_amdgcn_mfma_f32_16x16x32_bf16(af[mi], bv[nj],
                                                                 oacc[mi][nj], 0, 0, 0);
    }
  }

  // epilogue: O /= l, write bf16 [b][t][h*128+d]
  const int b = bh >> 4, h = bh & 15;
#pragma unroll
  for (int mi = 0; mi < 2; ++mi)
#pragma unroll
    for (int r = 0; r < 4; ++r) {
      float rinv = 1.f / lst[mi][r];
      int t = q0 + wave * 32 + mi * 16 + quad * 4 + r;
      unsigned short* orow = Out + (((long)(b * T + t)) << 11) + h * 128;
#pragma unroll
      for (int nj = 0; nj < 8; ++nj)
        orow[nj * 16 + ln15] = f2bf(oacc[mi][nj][r] * rinv);
    }
}

extern "C" void kernel_launch(void* const* d_in, const int* in_sizes, int n_in,
                              void* d_out, int out_size, void* d_ws, size_t ws_size,
                              hipStream_t stream) {
  const float* x    = (const float*)d_in[0];
  const float* pos  = (const float*)d_in[1];
  const float* wq_w = (const float*)d_in[2];
  const float* wq_b = (const float*)d_in[3];
  const float* wk_w = (const float*)d_in[4];
  const float* wk_b = (const float*)d_in[5];
  const float* wv_w = (const float*)d_in[6];
  const float* wv_b = (const float*)d_in[7];
  const float* wo_w = (const float*)d_in[8];
  const float* wo_b = (const float*)d_in[9];

  unsigned short* xb  = (unsigned short*)d_ws;
  unsigned short* wqb = xb  + (1u << 24);
  unsigned short* wkb = wqb + (1u << 22);
  unsigned short* wvb = wkb + (1u << 22);
  unsigned short* wob = wvb + (1u << 22);
  unsigned short* qb  = wob + (1u << 22);
  unsigned short* kb  = qb  + (1u << 24);
  unsigned short* vtb = kb  + (1u << 24);
  unsigned short* ab  = vtb + (1u << 24);   // attention output, bf16 [8192][2048]

  cast_kernel<<<16384, 256, 0, stream>>>((const float4*)x, (ushortx4*)xb);
  cast_kernel<<<4096, 256, 0, stream>>>((const float4*)wq_w, (ushortx4*)wqb);
  cast_kernel<<<4096, 256, 0, stream>>>((const float4*)wk_w, (ushortx4*)wkb);
  cast_kernel<<<4096, 256, 0, stream>>>((const float4*)wv_w, (ushortx4*)wvb);
  cast_kernel<<<4096, 256, 0, stream>>>((const float4*)wo_w, (ushortx4*)wob);

  gemm_bt<0><<<1024, 256, 0, stream>>>(xb, wqb, wq_b, (void*)qb);
  gemm_bt<0><<<1024, 256, 0, stream>>>(xb, wkb, wk_b, (void*)kb);
  gemm_bt<1><<<1024, 256, 0, stream>>>(xb, wvb, wv_b, (void*)vtb);
  rope_kernel<<<65536, 256, 0, stream>>>(qb, kb, pos);
  flash_kernel<<<1024, 256, 0, stream>>>(qb, kb, vtb, ab);
  gemm_bt<2><<<1024, 256, 0, stream>>>(ab, wob, wo_b, d_out);
}